// Round 10
// baseline (208.838 us; speedup 1.0000x reference)
//
#include <hip/hip_runtime.h>
#include <math.h>

// ---------------------------------------------------------------------------
// Deformable transformer layer, MI355X round-25:
//  - prep_all / deform_fused / wp_mlp kept (rounds 10-24; wp_mlp now 44us,
//    no spill, matched prediction).
//  - NEW: gemm_oa_v rebuilt as gemm_oa_v2 in the proven wp_mlp style:
//    64-row blocks (grid 256 oa + 197 v), 1024 threads, A staged once via
//    glds16 (rotated), B FRAG-MAJOR direct from L2, ZERO barriers in K-loop.
//    Output staged in padded LDS (292/268-short rows, bank-clean) for
//    coalesced stores. 70144 B LDS. Replaces the last round-10-era
//    stage->vmcnt(0)->barrier core.
//  - prep_all: ALL weights now frag-major packed (wt_oa 196608 B exact fit).
//  4 dispatches.
// B=2, Nq=8192, C=256, HEADS=8, dh=32, LEVELS=3, POINTS=4, MLP=4
// ---------------------------------------------------------------------------

typedef short short8 __attribute__((ext_vector_type(8)));
typedef short s16x4 __attribute__((ext_vector_type(4)));
typedef __bf16 bf16x8 __attribute__((ext_vector_type(8)));
typedef float f32x4 __attribute__((ext_vector_type(4)));

__device__ __forceinline__ short f2b(float f) {
  unsigned u = __builtin_bit_cast(unsigned, f);
  u += 0x7fffu + ((u >> 16) & 1u);   // RNE to bf16
  return (short)(u >> 16);
}
__device__ __forceinline__ float b2f(short s) {
  unsigned u = ((unsigned)(unsigned short)s) << 16;
  return __builtin_bit_cast(float, u);
}
__device__ __forceinline__ void b8f(short8 s, float* f) {
  const uint4 u = __builtin_bit_cast(uint4, s);
  f[0] = __builtin_bit_cast(float, u.x << 16);
  f[1] = __builtin_bit_cast(float, u.x & 0xffff0000u);
  f[2] = __builtin_bit_cast(float, u.y << 16);
  f[3] = __builtin_bit_cast(float, u.y & 0xffff0000u);
  f[4] = __builtin_bit_cast(float, u.z << 16);
  f[5] = __builtin_bit_cast(float, u.z & 0xffff0000u);
  f[6] = __builtin_bit_cast(float, u.w << 16);
  f[7] = __builtin_bit_cast(float, u.w & 0xffff0000u);
}

__device__ __forceinline__ f32x4 mfma16(short8 a, short8 b, f32x4 c) {
  return __builtin_amdgcn_mfma_f32_16x16x32_bf16(
      __builtin_bit_cast(bf16x8, a), __builtin_bit_cast(bf16x8, b), c, 0, 0, 0);
}

typedef __attribute__((address_space(3))) unsigned int lds_u32;
typedef const __attribute__((address_space(1))) unsigned int glb_u32;
__device__ __forceinline__ void glds16(const void* g, void* l) {
  __builtin_amdgcn_global_load_lds((glb_u32*)g, (lds_u32*)l, 16, 0, 0);
}

__device__ __forceinline__ float gelu1(float v) {
  return 0.5f * v * (1.f + erff(v * 0.70710678118654752f));
}

// ---------------------------------------------------------------------------
// gemm_oa_v2: blocks [0,256) -> oa (M=16384, N=384 padded, 288 real, bf16),
//             blocks [256,453) -> v (M=12600, N=256, bf16).
// Per 64-row block, 1024 threads (16 waves, 2M x 8N):
//   RA = A rows (rotated, glds16) ; B frag-major direct from L2, no barriers
//   in the K-loop (K=256, 8 chunks). Output staged in padded LDS rows
//   (oa ld=292, v ld=268 shorts: 8B-aligned rows, 16-distinct-bank writes),
//   then coalesced row-major stores.
// ---------------------------------------------------------------------------
__global__ __launch_bounds__(1024) void gemm_oa_v2(
    const short* __restrict__ qa, const short* __restrict__ wt_oa,
    const float* __restrict__ bo, const float* __restrict__ ba,
    short* __restrict__ oabuf,
    const short* __restrict__ valbf, const short* __restrict__ wt_v,
    const float* __restrict__ bv, short* __restrict__ vproj)
{
  __shared__ __align__(16) char smem[70144];
  short* stg = (short*)smem;            // oa: [64][292], v: [64][268]
  short* RA  = (short*)(smem + 37376);  // [64][256] bf16 rotated (32 KB)

  const int t = threadIdx.x;
  const int w = t >> 6, lane = t & 63;
  const int quad = lane >> 4, l16 = lane & 15;
  const int wm2 = w >> 3, wn8 = w & 7;   // 2M x 8N wave grid
  const bool is_oa = blockIdx.x < 256;
  const int m0 = (is_oa ? blockIdx.x : (blockIdx.x - 256)) * 64;
  const short* A  = is_oa ? qa : valbf;
  const short* wt = is_oa ? wt_oa : wt_v;

  // ---- stage A -> RA (rotated, 2 glds16/thread) --------------------------
#pragma unroll
  for (int qq = 0; qq < 2; ++qq) {
    const int g = qq * 1024 + t;
    const int row = g >> 5, p = g & 31;
    const int cl = (p & ~7) | ((p + row) & 7);
    glds16(A + (size_t)(m0 + row) * 256 + cl * 8,
           RA + (qq * 1024 + w * 64) * 8);
  }
  __syncthreads();

  if (is_oa) {
    // ---- oa GEMM: acc[2][3] (wave covers 48 of 384 cols) -----------------
    f32x4 acc[2][3];
#pragma unroll
    for (int i = 0; i < 2; i++)
#pragma unroll
      for (int j = 0; j < 3; j++) acc[i][j] = (f32x4){0.f, 0.f, 0.f, 0.f};
#pragma unroll
    for (int kk = 0; kk < 8; ++kk) {
      const int c = kk * 4 + quad;
      short8 afr[2], bfr[3];
#pragma unroll
      for (int i = 0; i < 2; ++i) {
        const int r = wm2 * 32 + i * 16 + l16;
        const int pos = (c & ~7) | ((c - r) & 7);
        afr[i] = *(const short8*)(RA + r * 256 + pos * 8);
      }
#pragma unroll
      for (int j = 0; j < 3; ++j) {
        const int n1 = wn8 * 3 + j;
        bfr[j] = *(const short8*)(wt + ((size_t)n1 * 32 + c) * 128 + l16 * 8);
      }
#pragma unroll
      for (int i = 0; i < 2; ++i)
#pragma unroll
        for (int j = 0; j < 3; ++j) acc[i][j] = mfma16(bfr[j], afr[i], acc[i][j]);
    }
    // bias + bf16 -> stg (cols < 288 only; 288..383 are pad)
#pragma unroll
    for (int i = 0; i < 2; ++i)
#pragma unroll
      for (int j = 0; j < 3; ++j) {
        const int col = (wn8 * 3 + j) * 16 + quad * 4;
        if (col < 288) {
          const int r = wm2 * 32 + i * 16 + l16;
          const float4 bb = (col < 192) ? *(const float4*)(bo + col)
                                        : *(const float4*)(ba + col - 192);
          s16x4 o;
          o.x = f2b(acc[i][j].x + bb.x); o.y = f2b(acc[i][j].y + bb.y);
          o.z = f2b(acc[i][j].z + bb.z); o.w = f2b(acc[i][j].w + bb.w);
          *(s16x4*)(stg + r * 292 + col) = o;
        }
      }
    __syncthreads();
    // coalesced store 64 x 288
    for (int e = t; e < 4608; e += 1024) {
      const int row = e / 72, c4 = (e % 72) * 4;
      *(s16x4*)(oabuf + (size_t)(m0 + row) * 288 + c4) =
          *(const s16x4*)(stg + row * 292 + c4);
    }
  } else {
    // ---- v GEMM: acc[2][2] (wave covers 32 of 256 cols) ------------------
    f32x4 acc[2][2];
#pragma unroll
    for (int i = 0; i < 2; i++)
#pragma unroll
      for (int j = 0; j < 2; j++) acc[i][j] = (f32x4){0.f, 0.f, 0.f, 0.f};
#pragma unroll
    for (int kk = 0; kk < 8; ++kk) {
      const int c = kk * 4 + quad;
      short8 afr[2], bfr[2];
#pragma unroll
      for (int i = 0; i < 2; ++i) {
        const int r = wm2 * 32 + i * 16 + l16;
        const int pos = (c & ~7) | ((c - r) & 7);
        afr[i] = *(const short8*)(RA + r * 256 + pos * 8);
      }
#pragma unroll
      for (int j = 0; j < 2; ++j) {
        const int n1 = wn8 * 2 + j;
        bfr[j] = *(const short8*)(wt + ((size_t)n1 * 32 + c) * 128 + l16 * 8);
      }
#pragma unroll
      for (int i = 0; i < 2; ++i)
#pragma unroll
        for (int j = 0; j < 2; ++j) acc[i][j] = mfma16(bfr[j], afr[i], acc[i][j]);
    }
#pragma unroll
    for (int i = 0; i < 2; ++i)
#pragma unroll
      for (int j = 0; j < 2; ++j) {
        const int col = (wn8 * 2 + j) * 16 + quad * 4;
        const int r = wm2 * 32 + i * 16 + l16;
        const float4 bb = *(const float4*)(bv + col);
        s16x4 o;
        o.x = f2b(acc[i][j].x + bb.x); o.y = f2b(acc[i][j].y + bb.y);
        o.z = f2b(acc[i][j].z + bb.z); o.w = f2b(acc[i][j].w + bb.w);
        *(s16x4*)(stg + r * 268 + col) = o;
      }
    __syncthreads();
    // coalesced store 64 x 256 (guard M=12600 tail)
    for (int e = t; e < 4096; e += 1024) {
      const int row = e >> 6, c4 = (e & 63) * 4;
      const int gm = m0 + row;
      if (gm < 12600)
        *(s16x4*)(vproj + (size_t)gm * 256 + c4) =
            *(const s16x4*)(stg + row * 268 + c4);
    }
  }
}

// ---------------------------------------------------------------------------
// wp_mlp: per 64-row block (grid 256, 1024 threads, 128 KB LDS, 16 waves/CU):
//   Q  = sampled@Wp (XOR-swz) -> qbuf in-place -> final out in-place
//   RA = sampled (rotated) -> q2 (rotated)
//   H  = one 256-col quarter of hidden (rotated), 4 quarters total
//   out = Q (qbuf + H@Wf2 + bf2, accumulated in place)
// Weights read ONCE per block (grid 256 = 1/CU). acc1/acc2 2x2 -> no spill.
// ---------------------------------------------------------------------------
__global__ __launch_bounds__(1024) void wp_mlp(
    const short* __restrict__ sampled,  // [16384][256] bf16
    const short* __restrict__ wtp,      // frag-major K=256 N=256
    const float* __restrict__ bp,
    const short* __restrict__ qnb,      // [16384][256] bf16
    const float* __restrict__ query,    // [16384][256] f32
    const float* __restrict__ g2, const float* __restrict__ b2v,
    const short* __restrict__ wf1,      // frag-major K=256 N=1024
    const float* __restrict__ b1v,
    const short* __restrict__ wf2,      // frag-major K=1024 N=256
    const float* __restrict__ bf2v,
    float* __restrict__ outp)           // [16384][256] f32
{
  __shared__ __align__(16) char smem[131072];
  float* Q  = (float*)smem;             // [64][256] f32, XOR-swz (64 KB)
  short* H  = (short*)(smem + 65536);   // [64][256] bf16 quarter (32 KB)
  short* RA = (short*)(smem + 98304);   // [64][256] bf16 rotated (32 KB)

  const int t = threadIdx.x;
  const int w = t >> 6, lane = t & 63;
  const int quad = lane >> 4, l16 = lane & 15;
  const int wm2 = w >> 3, wn8 = w & 7;   // 2M x 8N wave grid
  const int m0 = blockIdx.x * 64;

  // ---- stage sampled -> RA (rotated, 2 glds16/thread) --------------------
#pragma unroll
  for (int qq = 0; qq < 2; ++qq) {
    const int g = qq * 1024 + t;
    const int row = g >> 5, p = g & 31;
    const int cl = (p & ~7) | ((p + row) & 7);
    glds16(sampled + (size_t)(m0 + row) * 256 + cl * 8,
           RA + (qq * 1024 + w * 64) * 8);
  }
  __syncthreads();

  // ---- wp GEMM: acc[2][2], K=256 (32 chunks), no barriers ---------------
  {
    f32x4 accp[2][2];
#pragma unroll
    for (int i = 0; i < 2; i++)
#pragma unroll
      for (int j = 0; j < 2; j++) accp[i][j] = (f32x4){0.f, 0.f, 0.f, 0.f};
#pragma unroll
    for (int kk = 0; kk < 8; ++kk) {
      const int c = kk * 4 + quad;
      short8 afr[2], bfr[2];
#pragma unroll
      for (int i = 0; i < 2; ++i) {
        const int r = wm2 * 32 + i * 16 + l16;
        const int pos = (c & ~7) | ((c - r) & 7);
        afr[i] = *(const short8*)(RA + r * 256 + pos * 8);
      }
#pragma unroll
      for (int j = 0; j < 2; ++j) {
        const int n1 = wn8 * 2 + j;
        bfr[j] = *(const short8*)(wtp + ((size_t)n1 * 32 + c) * 128 + l16 * 8);
      }
#pragma unroll
      for (int i = 0; i < 2; ++i)
#pragma unroll
        for (int j = 0; j < 2; ++j) accp[i][j] = mfma16(bfr[j], afr[i], accp[i][j]);
    }
    // stage wp acc into Q (XOR-swz: col ^ ((row&7)<<2))
#pragma unroll
    for (int i = 0; i < 2; ++i)
#pragma unroll
      for (int j = 0; j < 2; ++j) {
        const int r = wm2 * 32 + i * 16 + l16;
        const int cc = wn8 * 32 + j * 16 + quad * 4;
        *(f32x4*)&Q[r * 256 + (cc ^ ((r & 7) << 2))] = accp[i][j];
      }
  }
  __syncthreads();   // Q (wp acc) ready; RA (sampled) reads done

  // ---- LN2: wave w owns rows {w, 16+w, 32+w, 48+w}; qbuf in-place in Q ---
  {
    const float4 bbp  = *(const float4*)(bp + lane * 4);
    const float4 gv   = *(const float4*)(g2 + lane * 4);
    const float4 bb2  = *(const float4*)(b2v + lane * 4);
#pragma unroll
    for (int rep = 0; rep < 4; ++rep) {
      const int row = rep * 16 + w;
      const int gm = m0 + row;
      const int cs = (lane * 4) ^ ((row & 7) << 2);
      const float4 a  = *(const float4*)&Q[row * 256 + cs];
      const float4 qv = *(const float4*)(query + (size_t)gm * 256 + lane * 4);
      const s16x4 qn  = *(const s16x4*)(qnb + (size_t)gm * 256 + lane * 4);
      float v0 = a.x + bbp.x + b2f(qn.x) + qv.x;
      float v1 = a.y + bbp.y + b2f(qn.y) + qv.y;
      float v2 = a.z + bbp.z + b2f(qn.z) + qv.z;
      float v3 = a.w + bbp.w + b2f(qn.w) + qv.w;
      float s = v0 + v1 + v2 + v3;
#pragma unroll
      for (int o = 32; o; o >>= 1) s += __shfl_xor(s, o);
      const float mean = s * (1.f / 256.f);
      const float d0 = v0 - mean, d1 = v1 - mean, d2 = v2 - mean, d3 = v3 - mean;
      float ss = d0 * d0 + d1 * d1 + d2 * d2 + d3 * d3;
#pragma unroll
      for (int o = 32; o; o >>= 1) ss += __shfl_xor(ss, o);
      const float inv = rsqrtf(ss * (1.f / 256.f) + 1e-5f);
      *(f32x4*)&Q[row * 256 + cs] = (f32x4){v0, v1, v2, v3};  // qbuf
      const int col = lane * 4;
      const int c = col >> 3;
      const int pos = (c & ~7) | ((c - row) & 7);
      s16x4 o2;
      o2.x = f2b(d0 * inv * gv.x + bb2.x);
      o2.y = f2b(d1 * inv * gv.y + bb2.y);
      o2.z = f2b(d2 * inv * gv.z + bb2.z);
      o2.w = f2b(d3 * inv * gv.w + bb2.w);
      *(s16x4*)(RA + row * 256 + pos * 8 + (col & 7)) = o2;
    }
  }
  __syncthreads();   // RA = q2 ready

  // ---- MLP in four 256-col quarters of H ---------------------------------
  f32x4 acc2[2][2];
#pragma unroll
  for (int i = 0; i < 2; i++)
#pragma unroll
    for (int j = 0; j < 2; j++) acc2[i][j] = (f32x4){0.f, 0.f, 0.f, 0.f};

  for (int q = 0; q < 4; ++q) {
    if (q) __syncthreads();            // prior quarter's H reads done
    // phase-1: H-quarter = gelu(q2 @ Wf1[:, q*256:+256] + b1)
    f32x4 acc1[2][2];
#pragma unroll
    for (int i = 0; i < 2; i++)
#pragma unroll
      for (int j = 0; j < 2; j++) acc1[i][j] = (f32x4){0.f, 0.f, 0.f, 0.f};
#pragma unroll
    for (int kk = 0; kk < 8; ++kk) {
      const int cg = kk * 4 + quad;
      short8 afr[2], bfr[2];
#pragma unroll
      for (int i = 0; i < 2; ++i) {
        const int r = wm2 * 32 + i * 16 + l16;
        const int pos = (cg & ~7) | ((cg - r) & 7);
        afr[i] = *(const short8*)(RA + r * 256 + pos * 8);
      }
#pragma unroll
      for (int j = 0; j < 2; ++j) {
        const int n1 = q * 16 + wn8 * 2 + j;
        bfr[j] = *(const short8*)(wf1 + ((size_t)n1 * 32 + cg) * 128 + l16 * 8);
      }
#pragma unroll
      for (int i = 0; i < 2; ++i)
#pragma unroll
        for (int j = 0; j < 2; ++j) acc1[i][j] = mfma16(bfr[j], afr[i], acc1[i][j]);
    }
    // bias + gelu -> bf16 -> H-quarter (rotated)
#pragma unroll
    for (int j = 0; j < 2; ++j) {
      const int coll = wn8 * 32 + j * 16 + quad * 4;   // local col [0,256)
      const float4 bb = *(const float4*)(b1v + q * 256 + coll);
      const int c = coll >> 3;
#pragma unroll
      for (int i = 0; i < 2; ++i) {
        const int r = wm2 * 32 + i * 16 + l16;
        const int pos = (c & ~7) | ((c - r) & 7);
        s16x4 o;
        o.x = f2b(gelu1(acc1[i][j].x + bb.x));
        o.y = f2b(gelu1(acc1[i][j].y + bb.y));
        o.z = f2b(gelu1(acc1[i][j].z + bb.z));
        o.w = f2b(gelu1(acc1[i][j].w + bb.w));
        *(s16x4*)(H + r * 256 + pos * 8 + (coll & 7)) = o;
      }
    }
    __syncthreads();                   // H-quarter complete

    // phase-2: acc2 += H-quarter @ Wf2[q*256:+256, :]
#pragma unroll 4
    for (int kk = 0; kk < 8; ++kk) {
      const int cl = kk * 4 + quad;    // local chunk [0,32)
      short8 afr[2], bfr[2];
#pragma unroll
      for (int i = 0; i < 2; ++i) {
        const int r = wm2 * 32 + i * 16 + l16;
        const int pos = (cl & ~7) | ((cl - r) & 7);
        afr[i] = *(const short8*)(H + r * 256 + pos * 8);
      }
#pragma unroll
      for (int j = 0; j < 2; ++j) {
        const int n1 = wn8 * 2 + j;
        bfr[j] = *(const short8*)(wf2 + ((size_t)n1 * 128 + q * 32 + cl) * 128 + l16 * 8);
      }
#pragma unroll
      for (int i = 0; i < 2; ++i)
#pragma unroll
        for (int j = 0; j < 2; ++j) acc2[i][j] = mfma16(bfr[j], afr[i], acc2[i][j]);
    }
  }

  // ---- final add IN PLACE into Q (fragment-owned, race-free) -------------
  {
#pragma unroll
    for (int i = 0; i < 2; ++i)
#pragma unroll
      for (int j = 0; j < 2; ++j) {
        const int r = wm2 * 32 + i * 16 + l16;
        const int cc = wn8 * 32 + j * 16 + quad * 4;
        const int cs = cc ^ ((r & 7) << 2);
        const float4 bb = *(const float4*)(bf2v + cc);
        const float4 qb = *(const float4*)&Q[r * 256 + cs];
        *(f32x4*)&Q[r * 256 + cs] =
            (f32x4){qb.x + acc2[i][j].x + bb.x, qb.y + acc2[i][j].y + bb.y,
                    qb.z + acc2[i][j].z + bb.z, qb.w + acc2[i][j].w + bb.w};
      }
  }
  __syncthreads();   // all in-place adds visible

  // ---- coalesced store of Q -> out ---------------------------------------
#pragma unroll
  for (int rep = 0; rep < 4; ++rep) {
    const int row = rep * 16 + w;
    const int gm = m0 + row;
    const int cs = (lane * 4) ^ ((row & 7) << 2);
    const float4 v = *(const float4*)&Q[row * 256 + cs];
    *(float4*)(outp + (size_t)gm * 256 + lane * 4) = v;
  }
}

// ---------------------------------------------------------------------------
// prep_all: merged wconvert (1792 blocks) + vconvert (3169) + LN1 (4096).
// ALL weights packed FRAGMENT-MAJOR for direct-global B loads.
// ---------------------------------------------------------------------------
__global__ __launch_bounds__(256) void prep_all(
    const float* __restrict__ Wo, const float* __restrict__ Wa,
    const float* __restrict__ Wv, const float* __restrict__ Wp,
    const float* __restrict__ Wf1, const float* __restrict__ Wf2,
    short* __restrict__ t_oa, short* __restrict__ t_v, short* __restrict__ t_p,
    short* __restrict__ t_f1, short* __restrict__ t_f2,
    const float* __restrict__ value, short* __restrict__ valbf,
    const float* __restrict__ query, const float* __restrict__ query_pos,
    const float* __restrict__ g1, const float* __restrict__ b1,
    short* __restrict__ qnb, short* __restrict__ qa)
{
  __shared__ float tile[32][33];
  const int t = threadIdx.x;
  const int blk = blockIdx.x;

  if (blk < 1792) {
    const int bxa = blk & 255, bya = blk >> 8;
    int K, N, noff; const float* src; short* dst;
    switch (bya) {
      case 0: src = Wo;      dst = t_oa; K = 256;  N = 192;  noff = 0;   break;
      case 1: src = Wa;      dst = t_oa; K = 256;  N = 96;   noff = 192; break;
      case 2: src = nullptr; dst = t_oa; K = 256;  N = 96;   noff = 288; break;
      case 3: src = Wv;      dst = t_v;  K = 256;  N = 256;  noff = 0;   break;
      case 4: src = Wp;      dst = t_p;  K = 256;  N = 256;  noff = 0;   break;
      case 5: src = Wf1;     dst = t_f1; K = 256;  N = 1024; noff = 0;   break;
      default: src = Wf2;    dst = t_f2; K = 1024; N = 256;  noff = 0;   break;
    }
    const int tilesK = K >> 5;
    const int nt = tilesK * (N >> 5);
    if (bxa >= nt) return;
    const int tk = bxa % tilesK, tn = bxa / tilesK;
    const int k0 = tk * 32, n0 = tn * 32;
    const int r = t >> 3, c4 = (t & 7) * 4;
    float4 v = make_float4(0.f, 0.f, 0.f, 0.f);
    if (src) v = *(const float4*)(src + (size_t)(k0 + r) * N + n0 + c4);
    tile[r][c4] = v.x; tile[r][c4 + 1] = v.y; tile[r][c4 + 2] = v.z; tile[r][c4 + 3] = v.w;
    __syncthreads();
    const int nn = t >> 3, kc = (t & 7) * 4;
    s16x4 o;
    o.x = f2b(tile[kc][nn]); o.y = f2b(tile[kc + 1][nn]);
    o.z = f2b(tile[kc + 2][nn]); o.w = f2b(tile[kc + 3][nn]);
    // frag-major: addr(n,k) = ((n>>4)*(K>>3) + (k>>3))*128 + (n&15)*8 + (k&7)
    const int n = noff + n0 + nn, k = k0 + kc;
    *(s16x4*)(dst + ((size_t)(n >> 4) * (K >> 3) + (k >> 3)) * 128 +
              (n & 15) * 8 + (k & 7)) = o;
  } else if (blk < 1792 + 3169) {
    const int i = ((blk - 1792) * 256 + t) * 4;
    if (i >= 12672 * 256) return;
    s16x4 o = (s16x4){0, 0, 0, 0};
    if (i < 12600 * 256) {
      float4 v = *(const float4*)(value + i);
      o.x = f2b(v.x); o.y = f2b(v.y); o.z = f2b(v.z); o.w = f2b(v.w);
    }
    *(s16x4*)(valbf + i) = o;
  } else {
    const int row  = (blk - 4961) * 4 + (t >> 6);
    const int lane = t & 63;
    const float4 v = ((const float4*)(query + (size_t)row * 256))[lane];
    float s = v.x + v.y + v.z + v.w;
#pragma unroll
    for (int o = 32; o; o >>= 1) s += __shfl_xor(s, o);
    const float mean = s * (1.f / 256.f);
    const float dx = v.x - mean, dy = v.y - mean, dz = v.z - mean, dw = v.w - mean;
    float s2 = dx * dx + dy * dy + dz * dz + dw * dw;
#pragma unroll
    for (int o = 32; o; o >>= 1) s2 += __shfl_xor(s2, o);
    const float inv = rsqrtf(s2 * (1.f / 256.f) + 1e-5f);
    const float4 gv = ((const float4*)g1)[lane];
    const float4 bv = ((const float4*)b1)[lane];
    const float4 o1 = make_float4(dx * inv * gv.x + bv.x, dy * inv * gv.y + bv.y,
                                  dz * inv * gv.z + bv.z, dw * inv * gv.w + bv.w);
    s16x4 ob; ob.x = f2b(o1.x); ob.y = f2b(o1.y); ob.z = f2b(o1.z); ob.w = f2b(o1.w);
    ((s16x4*)(qnb + (size_t)row * 256))[lane] = ob;
    const float4 pv = ((const float4*)(query_pos + (size_t)row * 256))[lane];
    s16x4 op;
    op.x = f2b(o1.x + pv.x); op.y = f2b(o1.y + pv.y);
    op.z = f2b(o1.z + pv.z); op.w = f2b(o1.w + pv.w);
    ((s16x4*)(qa + (size_t)row * 256))[lane] = op;
  }
}

// ---------------------------------------------------------------------------
// deform_fused: block = 8 rows. Phase 1 (64 threads): softmax + bilinear
// setup -> LDS tables (oa bf16). Phase 2 (256 threads): gather+FMA.
// ---------------------------------------------------------------------------
__global__ __launch_bounds__(256) void deform_fused(
    const short* __restrict__ vproj, const short* __restrict__ oa,
    const float* __restrict__ refp, short* __restrict__ out)
{
  __shared__ int4 sIdx[768];
  __shared__ s16x4 sW[768];
  const int t = threadIdx.x;

  if (t < 64) {
    const int row = blockIdx.x * 8 + (t >> 3), h = t & 7;
    const short* oarow = oa + (size_t)row * 288;
    float off[24];
    {
      const short8* op = (const short8*)(oarow + h * 24);  // 48 B, 16B-aligned
      b8f(op[0], off); b8f(op[1], off + 8); b8f(op[2], off + 16);
    }
    float lg[12];
    {
      const s16x4* ap = (const s16x4*)(oarow + 192 + h * 12);  // 8B-aligned
#pragma unroll
      for (int i = 0; i < 3; i++) {
        const s16x4 v = ap[i];
        lg[i * 4] = b2f(v.x); lg[i * 4 + 1] = b2f(v.y);
        lg[i * 4 + 2] = b2f(v.z); lg[i * 4 + 3] = b2f(v.w);
      }
    }
    const float* rp = refp + (size_t)row * 6;
    const float Rx[3] = {rp[0], rp[2], rp[4]}, Ry[3] = {rp[1], rp[3], rp[5]};
    float mx = lg[0];
#pragma unroll
    for (int i = 1; i < 12; i++) mx = fmaxf(mx, lg[i]);
    float sum = 0.f;
#pragma unroll
    for (int i = 0; i < 12; i++) { lg[i] = __expf(lg[i] - mx); sum += lg[i]; }
    const float inv = 1.f / sum;
    const int b = row >> 13;
    const int Hs[3] = {60, 30, 15}, Ws[3] = {80, 40, 20}, St[3] = {0, 4800, 6000};
#pragma unroll
    for (int p = 0; p < 12; p++) {
      const int l = p >> 2;
      const int W = Ws[l], H = Hs[l];
      const float gx = Rx[l] * W + off[p * 2]     - 0.5f;
      const float gy = Ry[l] * H + off[p * 2 + 1] - 0.5f;
      const float x0f = floorf(gx), y0f = floorf(gy);
      const float wx = gx - x0f, wy = gy - y0f;
      const int x0 = (int)x0f, y0 = (int)y0f;
      const float aw = lg[p] * inv;
      float cw[4] = {(1.f - wx) * (1.f - wy), wx * (1.f - wy),
                     (1.f - wx) * wy, wx * wy};
      const int base = b * 6300 + St[l];
      int ci[4];
#pragma unroll
      for (int k = 0; k < 4; k++) {
        const int xx = x0 + (k & 1), yy = y0 + (k >> 1);
        const bool valid = (xx >= 0) & (xx < W) & (yy >= 0) & (yy < H);
        const int xc = min(max(xx, 0), W - 1);
        const int yc = min(max(yy, 0), H - 1);
        ci[k] = ((base + yc * W + xc) << 8) + h * 32;
        cw[k] = valid ? cw[k] * aw : 0.f;
      }
      sIdx[t * 12 + p] = make_int4(ci[0], ci[1], ci[2], ci[3]);
      s16x4 wv; wv.x = f2b(cw[0]); wv.y = f2b(cw[1]); wv.z = f2b(cw[2]); wv.w = f2b(cw[3]);
      sW[t * 12 + p] = wv;
    }
  }
  __syncthreads();

  const int lu = t >> 2, c4 = (t & 3) * 8;
  float acc[8];
#pragma unroll
  for (int i = 0; i < 8; i++) acc[i] = 0.f;
#pragma unroll 2
  for (int p = 0; p < 12; p++) {
    const int4 idx = sIdx[lu * 12 + p];
    const s16x4 wb = sW[lu * 12 + p];
    const float w0 = b2f(wb.x), w1 = b2f(wb.y), w2 = b2f(wb.z), w3 = b2f(wb.w);
    const short8 v0 = *(const short8*)(vproj + idx.x + c4);
    const short8 v1 = *(const short8*)(vproj + idx.y + c4);
    const short8 v2 = *(const short8*)(vproj + idx.z + c4);
    const short8 v3 = *(const short8*)(vproj + idx.w + c4);
    float f0[8], f1[8], f2[8], f3[8];
    b8f(v0, f0); b8f(v1, f1); b8f(v2, f2); b8f(v3, f3);
#pragma unroll
    for (int j = 0; j < 8; j++)
      acc[j] += w0 * f0[j] + w1 * f1[j] + w2 * f2[j] + w3 * f3[j];
  }
  short8 o;
#pragma unroll
  for (int j = 0; j < 8; j++) o[j] = f2b(acc[j]);
  *(short8*)(out + (size_t)(blockIdx.x * 256 + t) * 8) = o;
}

// ---------------------------------------------------------------------------
// Launch
// ---------------------------------------------------------------------------
extern "C" void kernel_launch(void* const* d_in, const int* in_sizes, int n_in,
                              void* d_out, int out_size, void* d_ws, size_t ws_size,
                              hipStream_t stream)
{
  const float* query     = (const float*)d_in[0];
  const float* value     = (const float*)d_in[1];
  const float* query_pos = (const float*)d_in[2];
  const float* ref_pts   = (const float*)d_in[3];
  const float* g1  = (const float*)d_in[6];
  const float* b1  = (const float*)d_in[7];
  const float* Wo  = (const float*)d_in[8];
  const float* bo  = (const float*)d_in[9];
  const float* Wa  = (const float*)d_in[10];
  const float* ba  = (const float*)d_in[11];
  const float* Wv  = (const float*)d_in[12];
  const float* bv  = (const float*)d_in[13];
  const float* Wp  = (const float*)d_in[14];
  const float* bp  = (const float*)d_in[15];
  const float* g2  = (const float*)d_in[16];
  const float* b2  = (const float*)d_in[17];
  const float* Wf1 = (const float*)d_in[18];
  const float* bf1 = (const float*)d_in[19];
  const float* Wf2 = (const float*)d_in[20];
  const float* bf2 = (const float*)d_in[21];

  char* ws = (char*)d_ws;
  short* wt_oa   = (short*)(ws + 0);          // 384x256 frag-major (196608 B)
  short* wt_v    = (short*)(ws + 196608);     // frag-major (131072 B)
  short* wt_p    = (short*)(ws + 327680);     // frag-major packed
  short* wt_f1   = (short*)(ws + 458752);     // frag-major packed
  short* wt_f2   = (short*)(ws + 983040);     // frag-major packed
  short* qnb     = (short*)(ws + 1507328);    // 16384x256 bf16 (LN1, no pos)
  short* qa      = (short*)(ws + 18284544);   // 16384x256 bf16
  short* oabuf   = (short*)(ws + 26673152);   // 16384x288 bf16 (9.4 MB)
  short* vproj   = (short*)(ws + 45547520);   // 12600x256 bf16
  short* sampled = (short*)(ws + 51998720);   // 16384x256 bf16
  short* valbf   = (short*)(ws + 77164544);   // 12672x256 bf16
  float* outp = (float*)d_out;

  // 1. merged: weight convert/pack + value convert + LN1
  prep_all<<<9057, 256, 0, stream>>>(Wo, Wa, Wv, Wp, Wf1, Wf2,
                                     wt_oa, wt_v, wt_p, wt_f1, wt_f2,
                                     value, valbf, query, query_pos,
                                     g1, b1, qnb, qa);
  // 2. merged GEMMs: oa (256 blocks) + vproj (197 blocks), wp_mlp-style
  gemm_oa_v2<<<453, 1024, 0, stream>>>(qa, wt_oa, bo, ba, oabuf,
                                       valbf, wt_v, bv, vproj);
  // 3. fused prep+gather -> sampled bf16
  deform_fused<<<2048, 256, 0, stream>>>(vproj, oabuf, ref_pts, sampled);
  // 4. merged Wp-GEMM + LN2 + MLP (64-row block, 128 KB LDS, no spill)
  wp_mlp<<<256, 1024, 0, stream>>>(sampled, wt_p, bp, qnb, query, g2, b2,
                                   wt_f1, bf1, wt_f2, bf2, outp);
}

// Round 11
// 203.048 us; speedup vs baseline: 1.0285x; 1.0285x over previous
//
#include <hip/hip_runtime.h>
#include <math.h>

// ---------------------------------------------------------------------------
// Deformable transformer layer, MI355X round-26:
//  - wp_mlp / deform_fused kept (rounds 10-25; wp_mlp 44us, no spill).
//  - NEW: LN1 + value-convert moved INSIDE gemm_oa_v2 (per-row aligned with
//    the consuming blocks): oa-block computes LN1 in-kernel (port of the
//    proven LN2 pattern), writes qnb to HBM, qa ONLY to LDS (kills 16.8 MB
//    round-trip); v-block converts value f32->bf16 straight into rotated LDS
//    (kills 13 MB valbf round-trip + 3169 prep blocks).
//  - prep_all shrunk to prep_w: weight frag-packing only (1792 blocks).
//  4 dispatches.
// B=2, Nq=8192, C=256, HEADS=8, dh=32, LEVELS=3, POINTS=4, MLP=4
// ---------------------------------------------------------------------------

typedef short short8 __attribute__((ext_vector_type(8)));
typedef short s16x4 __attribute__((ext_vector_type(4)));
typedef __bf16 bf16x8 __attribute__((ext_vector_type(8)));
typedef float f32x4 __attribute__((ext_vector_type(4)));

__device__ __forceinline__ short f2b(float f) {
  unsigned u = __builtin_bit_cast(unsigned, f);
  u += 0x7fffu + ((u >> 16) & 1u);   // RNE to bf16
  return (short)(u >> 16);
}
__device__ __forceinline__ float b2f(short s) {
  unsigned u = ((unsigned)(unsigned short)s) << 16;
  return __builtin_bit_cast(float, u);
}
__device__ __forceinline__ void b8f(short8 s, float* f) {
  const uint4 u = __builtin_bit_cast(uint4, s);
  f[0] = __builtin_bit_cast(float, u.x << 16);
  f[1] = __builtin_bit_cast(float, u.x & 0xffff0000u);
  f[2] = __builtin_bit_cast(float, u.y << 16);
  f[3] = __builtin_bit_cast(float, u.y & 0xffff0000u);
  f[4] = __builtin_bit_cast(float, u.z << 16);
  f[5] = __builtin_bit_cast(float, u.z & 0xffff0000u);
  f[6] = __builtin_bit_cast(float, u.w << 16);
  f[7] = __builtin_bit_cast(float, u.w & 0xffff0000u);
}

__device__ __forceinline__ f32x4 mfma16(short8 a, short8 b, f32x4 c) {
  return __builtin_amdgcn_mfma_f32_16x16x32_bf16(
      __builtin_bit_cast(bf16x8, a), __builtin_bit_cast(bf16x8, b), c, 0, 0, 0);
}

typedef __attribute__((address_space(3))) unsigned int lds_u32;
typedef const __attribute__((address_space(1))) unsigned int glb_u32;
__device__ __forceinline__ void glds16(const void* g, void* l) {
  __builtin_amdgcn_global_load_lds((glb_u32*)g, (lds_u32*)l, 16, 0, 0);
}

__device__ __forceinline__ float gelu1(float v) {
  return 0.5f * v * (1.f + erff(v * 0.70710678118654752f));
}

// ---------------------------------------------------------------------------
// gemm_oa_v2: blocks [0,256) -> LN1 + oa GEMM (M=16384, N=384 pad/288 real),
//             blocks [256,453) -> value-convert + v GEMM (M=12600, N=256).
// Per 64-row block, 1024 threads (16 waves, 2M x 8N):
//   oa: LN1(query) in-kernel -> qnb (HBM) + qa (rotated LDS only);
//   v : value f32 -> bf16 rotated LDS (zero for rows >= 12600).
//   B frag-major direct from L2, no barriers in K-loop. Output staged in
//   padded LDS rows (292/268 shorts) for coalesced stores.
// ---------------------------------------------------------------------------
__global__ __launch_bounds__(1024) void gemm_oa_v2(
    const float* __restrict__ query, const float* __restrict__ query_pos,
    const float* __restrict__ g1, const float* __restrict__ b1,
    const short* __restrict__ wt_oa,
    const float* __restrict__ bo, const float* __restrict__ ba,
    short* __restrict__ qnb, short* __restrict__ oabuf,
    const float* __restrict__ value, const short* __restrict__ wt_v,
    const float* __restrict__ bv, short* __restrict__ vproj)
{
  __shared__ __align__(16) char smem[70144];
  short* stg = (short*)smem;            // oa: [64][292], v: [64][268]
  short* RA  = (short*)(smem + 37376);  // [64][256] bf16 rotated (32 KB)

  const int t = threadIdx.x;
  const int w = t >> 6, lane = t & 63;
  const int quad = lane >> 4, l16 = lane & 15;
  const int wm2 = w >> 3, wn8 = w & 7;   // 2M x 8N wave grid
  const bool is_oa = blockIdx.x < 256;
  const int m0 = (is_oa ? blockIdx.x : (blockIdx.x - 256)) * 64;

  if (is_oa) {
    // ---- LN1: wave w owns rows {w,16+w,32+w,48+w} ------------------------
    const float4 gv  = *(const float4*)(g1 + lane * 4);
    const float4 bv1 = *(const float4*)(b1 + lane * 4);
#pragma unroll
    for (int rep = 0; rep < 4; ++rep) {
      const int row = rep * 16 + w;
      const int gm = m0 + row;
      const float4 v = *(const float4*)(query + (size_t)gm * 256 + lane * 4);
      float s = v.x + v.y + v.z + v.w;
#pragma unroll
      for (int o = 32; o; o >>= 1) s += __shfl_xor(s, o);
      const float mean = s * (1.f / 256.f);
      const float dx = v.x - mean, dy = v.y - mean, dz = v.z - mean, dw = v.w - mean;
      float s2 = dx * dx + dy * dy + dz * dz + dw * dw;
#pragma unroll
      for (int o = 32; o; o >>= 1) s2 += __shfl_xor(s2, o);
      const float inv = rsqrtf(s2 * (1.f / 256.f) + 1e-5f);
      const float o0 = dx * inv * gv.x + bv1.x;
      const float o1 = dy * inv * gv.y + bv1.y;
      const float o2 = dz * inv * gv.z + bv1.z;
      const float o3 = dw * inv * gv.w + bv1.w;
      s16x4 ob; ob.x = f2b(o0); ob.y = f2b(o1); ob.z = f2b(o2); ob.w = f2b(o3);
      *(s16x4*)(qnb + (size_t)gm * 256 + lane * 4) = ob;
      const float4 pv = *(const float4*)(query_pos + (size_t)gm * 256 + lane * 4);
      s16x4 oq;
      oq.x = f2b(o0 + pv.x); oq.y = f2b(o1 + pv.y);
      oq.z = f2b(o2 + pv.z); oq.w = f2b(o3 + pv.w);
      const int col = lane * 4;
      const int c = col >> 3;
      const int pos = (c & ~7) | ((c - row) & 7);
      *(s16x4*)(RA + row * 256 + pos * 8 + (col & 7)) = oq;
    }
    __syncthreads();

    // ---- oa GEMM: acc[2][3] (wave covers 48 of 384 cols) -----------------
    f32x4 acc[2][3];
#pragma unroll
    for (int i = 0; i < 2; i++)
#pragma unroll
      for (int j = 0; j < 3; j++) acc[i][j] = (f32x4){0.f, 0.f, 0.f, 0.f};
#pragma unroll
    for (int kk = 0; kk < 8; ++kk) {
      const int c = kk * 4 + quad;
      short8 afr[2], bfr[3];
#pragma unroll
      for (int i = 0; i < 2; ++i) {
        const int r = wm2 * 32 + i * 16 + l16;
        const int pos = (c & ~7) | ((c - r) & 7);
        afr[i] = *(const short8*)(RA + r * 256 + pos * 8);
      }
#pragma unroll
      for (int j = 0; j < 3; ++j) {
        const int n1 = wn8 * 3 + j;
        bfr[j] = *(const short8*)(wt_oa + ((size_t)n1 * 32 + c) * 128 + l16 * 8);
      }
#pragma unroll
      for (int i = 0; i < 2; ++i)
#pragma unroll
        for (int j = 0; j < 3; ++j) acc[i][j] = mfma16(bfr[j], afr[i], acc[i][j]);
    }
    // bias + bf16 -> stg (cols < 288 only; 288..383 are pad)
#pragma unroll
    for (int i = 0; i < 2; ++i)
#pragma unroll
      for (int j = 0; j < 3; ++j) {
        const int col = (wn8 * 3 + j) * 16 + quad * 4;
        if (col < 288) {
          const int r = wm2 * 32 + i * 16 + l16;
          const float4 bb = (col < 192) ? *(const float4*)(bo + col)
                                        : *(const float4*)(ba + col - 192);
          s16x4 o;
          o.x = f2b(acc[i][j].x + bb.x); o.y = f2b(acc[i][j].y + bb.y);
          o.z = f2b(acc[i][j].z + bb.z); o.w = f2b(acc[i][j].w + bb.w);
          *(s16x4*)(stg + r * 292 + col) = o;
        }
      }
    __syncthreads();
    // coalesced store 64 x 288
    for (int e = t; e < 4608; e += 1024) {
      const int row = e / 72, c4 = (e % 72) * 4;
      *(s16x4*)(oabuf + (size_t)(m0 + row) * 288 + c4) =
          *(const s16x4*)(stg + row * 292 + c4);
    }
  } else {
    // ---- value f32 -> bf16 rotated RA (zero rows >= 12600) ---------------
#pragma unroll
    for (int rep = 0; rep < 4; ++rep) {
      const int row = rep * 16 + w;
      const int gm = m0 + row;
      float4 v = make_float4(0.f, 0.f, 0.f, 0.f);
      if (gm < 12600)
        v = *(const float4*)(value + (size_t)gm * 256 + lane * 4);
      s16x4 ob; ob.x = f2b(v.x); ob.y = f2b(v.y); ob.z = f2b(v.z); ob.w = f2b(v.w);
      const int col = lane * 4;
      const int c = col >> 3;
      const int pos = (c & ~7) | ((c - row) & 7);
      *(s16x4*)(RA + row * 256 + pos * 8 + (col & 7)) = ob;
    }
    __syncthreads();

    // ---- v GEMM: acc[2][2] (wave covers 32 of 256 cols) ------------------
    f32x4 acc[2][2];
#pragma unroll
    for (int i = 0; i < 2; i++)
#pragma unroll
      for (int j = 0; j < 2; j++) acc[i][j] = (f32x4){0.f, 0.f, 0.f, 0.f};
#pragma unroll
    for (int kk = 0; kk < 8; ++kk) {
      const int c = kk * 4 + quad;
      short8 afr[2], bfr[2];
#pragma unroll
      for (int i = 0; i < 2; ++i) {
        const int r = wm2 * 32 + i * 16 + l16;
        const int pos = (c & ~7) | ((c - r) & 7);
        afr[i] = *(const short8*)(RA + r * 256 + pos * 8);
      }
#pragma unroll
      for (int j = 0; j < 2; ++j) {
        const int n1 = wn8 * 2 + j;
        bfr[j] = *(const short8*)(wt_v + ((size_t)n1 * 32 + c) * 128 + l16 * 8);
      }
#pragma unroll
      for (int i = 0; i < 2; ++i)
#pragma unroll
        for (int j = 0; j < 2; ++j) acc[i][j] = mfma16(bfr[j], afr[i], acc[i][j]);
    }
#pragma unroll
    for (int i = 0; i < 2; ++i)
#pragma unroll
      for (int j = 0; j < 2; ++j) {
        const int col = (wn8 * 2 + j) * 16 + quad * 4;
        const int r = wm2 * 32 + i * 16 + l16;
        const float4 bb = *(const float4*)(bv + col);
        s16x4 o;
        o.x = f2b(acc[i][j].x + bb.x); o.y = f2b(acc[i][j].y + bb.y);
        o.z = f2b(acc[i][j].z + bb.z); o.w = f2b(acc[i][j].w + bb.w);
        *(s16x4*)(stg + r * 268 + col) = o;
      }
    __syncthreads();
    // coalesced store 64 x 256 (guard M=12600 tail)
    for (int e = t; e < 4096; e += 1024) {
      const int row = e >> 6, c4 = (e & 63) * 4;
      const int gm = m0 + row;
      if (gm < 12600)
        *(s16x4*)(vproj + (size_t)gm * 256 + c4) =
            *(const s16x4*)(stg + row * 268 + c4);
    }
  }
}

// ---------------------------------------------------------------------------
// wp_mlp: per 64-row block (grid 256, 1024 threads, 128 KB LDS, 16 waves/CU):
//   Q  = sampled@Wp (XOR-swz) -> qbuf in-place -> final out in-place
//   RA = sampled (rotated) -> q2 (rotated)
//   H  = one 256-col quarter of hidden (rotated), 4 quarters total
//   out = Q (qbuf + H@Wf2 + bf2, accumulated in place)
// ---------------------------------------------------------------------------
__global__ __launch_bounds__(1024) void wp_mlp(
    const short* __restrict__ sampled,  // [16384][256] bf16
    const short* __restrict__ wtp,      // frag-major K=256 N=256
    const float* __restrict__ bp,
    const short* __restrict__ qnb,      // [16384][256] bf16
    const float* __restrict__ query,    // [16384][256] f32
    const float* __restrict__ g2, const float* __restrict__ b2v,
    const short* __restrict__ wf1,      // frag-major K=256 N=1024
    const float* __restrict__ b1v,
    const short* __restrict__ wf2,      // frag-major K=1024 N=256
    const float* __restrict__ bf2v,
    float* __restrict__ outp)           // [16384][256] f32
{
  __shared__ __align__(16) char smem[131072];
  float* Q  = (float*)smem;             // [64][256] f32, XOR-swz (64 KB)
  short* H  = (short*)(smem + 65536);   // [64][256] bf16 quarter (32 KB)
  short* RA = (short*)(smem + 98304);   // [64][256] bf16 rotated (32 KB)

  const int t = threadIdx.x;
  const int w = t >> 6, lane = t & 63;
  const int quad = lane >> 4, l16 = lane & 15;
  const int wm2 = w >> 3, wn8 = w & 7;   // 2M x 8N wave grid
  const int m0 = blockIdx.x * 64;

  // ---- stage sampled -> RA (rotated, 2 glds16/thread) --------------------
#pragma unroll
  for (int qq = 0; qq < 2; ++qq) {
    const int g = qq * 1024 + t;
    const int row = g >> 5, p = g & 31;
    const int cl = (p & ~7) | ((p + row) & 7);
    glds16(sampled + (size_t)(m0 + row) * 256 + cl * 8,
           RA + (qq * 1024 + w * 64) * 8);
  }
  __syncthreads();

  // ---- wp GEMM: acc[2][2], K=256 (32 chunks), no barriers ---------------
  {
    f32x4 accp[2][2];
#pragma unroll
    for (int i = 0; i < 2; i++)
#pragma unroll
      for (int j = 0; j < 2; j++) accp[i][j] = (f32x4){0.f, 0.f, 0.f, 0.f};
#pragma unroll
    for (int kk = 0; kk < 8; ++kk) {
      const int c = kk * 4 + quad;
      short8 afr[2], bfr[2];
#pragma unroll
      for (int i = 0; i < 2; ++i) {
        const int r = wm2 * 32 + i * 16 + l16;
        const int pos = (c & ~7) | ((c - r) & 7);
        afr[i] = *(const short8*)(RA + r * 256 + pos * 8);
      }
#pragma unroll
      for (int j = 0; j < 2; ++j) {
        const int n1 = wn8 * 2 + j;
        bfr[j] = *(const short8*)(wtp + ((size_t)n1 * 32 + c) * 128 + l16 * 8);
      }
#pragma unroll
      for (int i = 0; i < 2; ++i)
#pragma unroll
        for (int j = 0; j < 2; ++j) accp[i][j] = mfma16(bfr[j], afr[i], accp[i][j]);
    }
    // stage wp acc into Q (XOR-swz: col ^ ((row&7)<<2))
#pragma unroll
    for (int i = 0; i < 2; ++i)
#pragma unroll
      for (int j = 0; j < 2; ++j) {
        const int r = wm2 * 32 + i * 16 + l16;
        const int cc = wn8 * 32 + j * 16 + quad * 4;
        *(f32x4*)&Q[r * 256 + (cc ^ ((r & 7) << 2))] = accp[i][j];
      }
  }
  __syncthreads();   // Q (wp acc) ready; RA (sampled) reads done

  // ---- LN2: wave w owns rows {w, 16+w, 32+w, 48+w}; qbuf in-place in Q ---
  {
    const float4 bbp  = *(const float4*)(bp + lane * 4);
    const float4 gv   = *(const float4*)(g2 + lane * 4);
    const float4 bb2  = *(const float4*)(b2v + lane * 4);
#pragma unroll
    for (int rep = 0; rep < 4; ++rep) {
      const int row = rep * 16 + w;
      const int gm = m0 + row;
      const int cs = (lane * 4) ^ ((row & 7) << 2);
      const float4 a  = *(const float4*)&Q[row * 256 + cs];
      const float4 qv = *(const float4*)(query + (size_t)gm * 256 + lane * 4);
      const s16x4 qn  = *(const s16x4*)(qnb + (size_t)gm * 256 + lane * 4);
      float v0 = a.x + bbp.x + b2f(qn.x) + qv.x;
      float v1 = a.y + bbp.y + b2f(qn.y) + qv.y;
      float v2 = a.z + bbp.z + b2f(qn.z) + qv.z;
      float v3 = a.w + bbp.w + b2f(qn.w) + qv.w;
      float s = v0 + v1 + v2 + v3;
#pragma unroll
      for (int o = 32; o; o >>= 1) s += __shfl_xor(s, o);
      const float mean = s * (1.f / 256.f);
      const float d0 = v0 - mean, d1 = v1 - mean, d2 = v2 - mean, d3 = v3 - mean;
      float ss = d0 * d0 + d1 * d1 + d2 * d2 + d3 * d3;
#pragma unroll
      for (int o = 32; o; o >>= 1) ss += __shfl_xor(ss, o);
      const float inv = rsqrtf(ss * (1.f / 256.f) + 1e-5f);
      *(f32x4*)&Q[row * 256 + cs] = (f32x4){v0, v1, v2, v3};  // qbuf
      const int col = lane * 4;
      const int c = col >> 3;
      const int pos = (c & ~7) | ((c - row) & 7);
      s16x4 o2;
      o2.x = f2b(d0 * inv * gv.x + bb2.x);
      o2.y = f2b(d1 * inv * gv.y + bb2.y);
      o2.z = f2b(d2 * inv * gv.z + bb2.z);
      o2.w = f2b(d3 * inv * gv.w + bb2.w);
      *(s16x4*)(RA + row * 256 + pos * 8 + (col & 7)) = o2;
    }
  }
  __syncthreads();   // RA = q2 ready

  // ---- MLP in four 256-col quarters of H ---------------------------------
  f32x4 acc2[2][2];
#pragma unroll
  for (int i = 0; i < 2; i++)
#pragma unroll
    for (int j = 0; j < 2; j++) acc2[i][j] = (f32x4){0.f, 0.f, 0.f, 0.f};

  for (int q = 0; q < 4; ++q) {
    if (q) __syncthreads();            // prior quarter's H reads done
    // phase-1: H-quarter = gelu(q2 @ Wf1[:, q*256:+256] + b1)
    f32x4 acc1[2][2];
#pragma unroll
    for (int i = 0; i < 2; i++)
#pragma unroll
      for (int j = 0; j < 2; j++) acc1[i][j] = (f32x4){0.f, 0.f, 0.f, 0.f};
#pragma unroll
    for (int kk = 0; kk < 8; ++kk) {
      const int cg = kk * 4 + quad;
      short8 afr[2], bfr[2];
#pragma unroll
      for (int i = 0; i < 2; ++i) {
        const int r = wm2 * 32 + i * 16 + l16;
        const int pos = (cg & ~7) | ((cg - r) & 7);
        afr[i] = *(const short8*)(RA + r * 256 + pos * 8);
      }
#pragma unroll
      for (int j = 0; j < 2; ++j) {
        const int n1 = q * 16 + wn8 * 2 + j;
        bfr[j] = *(const short8*)(wf1 + ((size_t)n1 * 32 + cg) * 128 + l16 * 8);
      }
#pragma unroll
      for (int i = 0; i < 2; ++i)
#pragma unroll
        for (int j = 0; j < 2; ++j) acc1[i][j] = mfma16(bfr[j], afr[i], acc1[i][j]);
    }
    // bias + gelu -> bf16 -> H-quarter (rotated)
#pragma unroll
    for (int j = 0; j < 2; ++j) {
      const int coll = wn8 * 32 + j * 16 + quad * 4;   // local col [0,256)
      const float4 bb = *(const float4*)(b1v + q * 256 + coll);
      const int c = coll >> 3;
#pragma unroll
      for (int i = 0; i < 2; ++i) {
        const int r = wm2 * 32 + i * 16 + l16;
        const int pos = (c & ~7) | ((c - r) & 7);
        s16x4 o;
        o.x = f2b(gelu1(acc1[i][j].x + bb.x));
        o.y = f2b(gelu1(acc1[i][j].y + bb.y));
        o.z = f2b(gelu1(acc1[i][j].z + bb.z));
        o.w = f2b(gelu1(acc1[i][j].w + bb.w));
        *(s16x4*)(H + r * 256 + pos * 8 + (coll & 7)) = o;
      }
    }
    __syncthreads();                   // H-quarter complete

    // phase-2: acc2 += H-quarter @ Wf2[q*256:+256, :]
#pragma unroll 4
    for (int kk = 0; kk < 8; ++kk) {
      const int cl = kk * 4 + quad;    // local chunk [0,32)
      short8 afr[2], bfr[2];
#pragma unroll
      for (int i = 0; i < 2; ++i) {
        const int r = wm2 * 32 + i * 16 + l16;
        const int pos = (cl & ~7) | ((cl - r) & 7);
        afr[i] = *(const short8*)(H + r * 256 + pos * 8);
      }
#pragma unroll
      for (int j = 0; j < 2; ++j) {
        const int n1 = wn8 * 2 + j;
        bfr[j] = *(const short8*)(wf2 + ((size_t)n1 * 128 + q * 32 + cl) * 128 + l16 * 8);
      }
#pragma unroll
      for (int i = 0; i < 2; ++i)
#pragma unroll
        for (int j = 0; j < 2; ++j) acc2[i][j] = mfma16(bfr[j], afr[i], acc2[i][j]);
    }
  }

  // ---- final add IN PLACE into Q (fragment-owned, race-free) -------------
  {
#pragma unroll
    for (int i = 0; i < 2; ++i)
#pragma unroll
      for (int j = 0; j < 2; ++j) {
        const int r = wm2 * 32 + i * 16 + l16;
        const int cc = wn8 * 32 + j * 16 + quad * 4;
        const int cs = cc ^ ((r & 7) << 2);
        const float4 bb = *(const float4*)(bf2v + cc);
        const float4 qb = *(const float4*)&Q[r * 256 + cs];
        *(f32x4*)&Q[r * 256 + cs] =
            (f32x4){qb.x + acc2[i][j].x + bb.x, qb.y + acc2[i][j].y + bb.y,
                    qb.z + acc2[i][j].z + bb.z, qb.w + acc2[i][j].w + bb.w};
      }
  }
  __syncthreads();   // all in-place adds visible

  // ---- coalesced store of Q -> out ---------------------------------------
#pragma unroll
  for (int rep = 0; rep < 4; ++rep) {
    const int row = rep * 16 + w;
    const int gm = m0 + row;
    const int cs = (lane * 4) ^ ((row & 7) << 2);
    const float4 v = *(const float4*)&Q[row * 256 + cs];
    *(float4*)(outp + (size_t)gm * 256 + lane * 4) = v;
  }
}

// ---------------------------------------------------------------------------
// prep_w: weight convert + FRAG-MAJOR pack only (1792 blocks).
// ---------------------------------------------------------------------------
__global__ __launch_bounds__(256) void prep_w(
    const float* __restrict__ Wo, const float* __restrict__ Wa,
    const float* __restrict__ Wv, const float* __restrict__ Wp,
    const float* __restrict__ Wf1, const float* __restrict__ Wf2,
    short* __restrict__ t_oa, short* __restrict__ t_v, short* __restrict__ t_p,
    short* __restrict__ t_f1, short* __restrict__ t_f2)
{
  __shared__ float tile[32][33];
  const int t = threadIdx.x;
  const int blk = blockIdx.x;

  const int bxa = blk & 255, bya = blk >> 8;
  int K, N, noff; const float* src; short* dst;
  switch (bya) {
    case 0: src = Wo;      dst = t_oa; K = 256;  N = 192;  noff = 0;   break;
    case 1: src = Wa;      dst = t_oa; K = 256;  N = 96;   noff = 192; break;
    case 2: src = nullptr; dst = t_oa; K = 256;  N = 96;   noff = 288; break;
    case 3: src = Wv;      dst = t_v;  K = 256;  N = 256;  noff = 0;   break;
    case 4: src = Wp;      dst = t_p;  K = 256;  N = 256;  noff = 0;   break;
    case 5: src = Wf1;     dst = t_f1; K = 256;  N = 1024; noff = 0;   break;
    default: src = Wf2;    dst = t_f2; K = 1024; N = 256;  noff = 0;   break;
  }
  const int tilesK = K >> 5;
  const int nt = tilesK * (N >> 5);
  if (bxa >= nt) return;
  const int tk = bxa % tilesK, tn = bxa / tilesK;
  const int k0 = tk * 32, n0 = tn * 32;
  const int r = t >> 3, c4 = (t & 7) * 4;
  float4 v = make_float4(0.f, 0.f, 0.f, 0.f);
  if (src) v = *(const float4*)(src + (size_t)(k0 + r) * N + n0 + c4);
  tile[r][c4] = v.x; tile[r][c4 + 1] = v.y; tile[r][c4 + 2] = v.z; tile[r][c4 + 3] = v.w;
  __syncthreads();
  const int nn = t >> 3, kc = (t & 7) * 4;
  s16x4 o;
  o.x = f2b(tile[kc][nn]); o.y = f2b(tile[kc + 1][nn]);
  o.z = f2b(tile[kc + 2][nn]); o.w = f2b(tile[kc + 3][nn]);
  // frag-major: addr(n,k) = ((n>>4)*(K>>3) + (k>>3))*128 + (n&15)*8 + (k&7)
  const int n = noff + n0 + nn, k = k0 + kc;
  *(s16x4*)(dst + ((size_t)(n >> 4) * (K >> 3) + (k >> 3)) * 128 +
            (n & 15) * 8 + (k & 7)) = o;
}

// ---------------------------------------------------------------------------
// deform_fused: block = 8 rows. Phase 1 (64 threads): softmax + bilinear
// setup -> LDS tables (oa bf16). Phase 2 (256 threads): gather+FMA.
// ---------------------------------------------------------------------------
__global__ __launch_bounds__(256) void deform_fused(
    const short* __restrict__ vproj, const short* __restrict__ oa,
    const float* __restrict__ refp, short* __restrict__ out)
{
  __shared__ int4 sIdx[768];
  __shared__ s16x4 sW[768];
  const int t = threadIdx.x;

  if (t < 64) {
    const int row = blockIdx.x * 8 + (t >> 3), h = t & 7;
    const short* oarow = oa + (size_t)row * 288;
    float off[24];
    {
      const short8* op = (const short8*)(oarow + h * 24);  // 48 B, 16B-aligned
      b8f(op[0], off); b8f(op[1], off + 8); b8f(op[2], off + 16);
    }
    float lg[12];
    {
      const s16x4* ap = (const s16x4*)(oarow + 192 + h * 12);  // 8B-aligned
#pragma unroll
      for (int i = 0; i < 3; i++) {
        const s16x4 v = ap[i];
        lg[i * 4] = b2f(v.x); lg[i * 4 + 1] = b2f(v.y);
        lg[i * 4 + 2] = b2f(v.z); lg[i * 4 + 3] = b2f(v.w);
      }
    }
    const float* rp = refp + (size_t)row * 6;
    const float Rx[3] = {rp[0], rp[2], rp[4]}, Ry[3] = {rp[1], rp[3], rp[5]};
    float mx = lg[0];
#pragma unroll
    for (int i = 1; i < 12; i++) mx = fmaxf(mx, lg[i]);
    float sum = 0.f;
#pragma unroll
    for (int i = 0; i < 12; i++) { lg[i] = __expf(lg[i] - mx); sum += lg[i]; }
    const float inv = 1.f / sum;
    const int b = row >> 13;
    const int Hs[3] = {60, 30, 15}, Ws[3] = {80, 40, 20}, St[3] = {0, 4800, 6000};
#pragma unroll
    for (int p = 0; p < 12; p++) {
      const int l = p >> 2;
      const int W = Ws[l], H = Hs[l];
      const float gx = Rx[l] * W + off[p * 2]     - 0.5f;
      const float gy = Ry[l] * H + off[p * 2 + 1] - 0.5f;
      const float x0f = floorf(gx), y0f = floorf(gy);
      const float wx = gx - x0f, wy = gy - y0f;
      const int x0 = (int)x0f, y0 = (int)y0f;
      const float aw = lg[p] * inv;
      float cw[4] = {(1.f - wx) * (1.f - wy), wx * (1.f - wy),
                     (1.f - wx) * wy, wx * wy};
      const int base = b * 6300 + St[l];
      int ci[4];
#pragma unroll
      for (int k = 0; k < 4; k++) {
        const int xx = x0 + (k & 1), yy = y0 + (k >> 1);
        const bool valid = (xx >= 0) & (xx < W) & (yy >= 0) & (yy < H);
        const int xc = min(max(xx, 0), W - 1);
        const int yc = min(max(yy, 0), H - 1);
        ci[k] = ((base + yc * W + xc) << 8) + h * 32;
        cw[k] = valid ? cw[k] * aw : 0.f;
      }
      sIdx[t * 12 + p] = make_int4(ci[0], ci[1], ci[2], ci[3]);
      s16x4 wv; wv.x = f2b(cw[0]); wv.y = f2b(cw[1]); wv.z = f2b(cw[2]); wv.w = f2b(cw[3]);
      sW[t * 12 + p] = wv;
    }
  }
  __syncthreads();

  const int lu = t >> 2, c4 = (t & 3) * 8;
  float acc[8];
#pragma unroll
  for (int i = 0; i < 8; i++) acc[i] = 0.f;
#pragma unroll 2
  for (int p = 0; p < 12; p++) {
    const int4 idx = sIdx[lu * 12 + p];
    const s16x4 wb = sW[lu * 12 + p];
    const float w0 = b2f(wb.x), w1 = b2f(wb.y), w2 = b2f(wb.z), w3 = b2f(wb.w);
    const short8 v0 = *(const short8*)(vproj + idx.x + c4);
    const short8 v1 = *(const short8*)(vproj + idx.y + c4);
    const short8 v2 = *(const short8*)(vproj + idx.z + c4);
    const short8 v3 = *(const short8*)(vproj + idx.w + c4);
    float f0[8], f1[8], f2[8], f3[8];
    b8f(v0, f0); b8f(v1, f1); b8f(v2, f2); b8f(v3, f3);
#pragma unroll
    for (int j = 0; j < 8; j++)
      acc[j] += w0 * f0[j] + w1 * f1[j] + w2 * f2[j] + w3 * f3[j];
  }
  short8 o;
#pragma unroll
  for (int j = 0; j < 8; j++) o[j] = f2b(acc[j]);
  *(short8*)(out + (size_t)(blockIdx.x * 256 + t) * 8) = o;
}

// ---------------------------------------------------------------------------
// Launch
// ---------------------------------------------------------------------------
extern "C" void kernel_launch(void* const* d_in, const int* in_sizes, int n_in,
                              void* d_out, int out_size, void* d_ws, size_t ws_size,
                              hipStream_t stream)
{
  const float* query     = (const float*)d_in[0];
  const float* value     = (const float*)d_in[1];
  const float* query_pos = (const float*)d_in[2];
  const float* ref_pts   = (const float*)d_in[3];
  const float* g1  = (const float*)d_in[6];
  const float* b1  = (const float*)d_in[7];
  const float* Wo  = (const float*)d_in[8];
  const float* bo  = (const float*)d_in[9];
  const float* Wa  = (const float*)d_in[10];
  const float* ba  = (const float*)d_in[11];
  const float* Wv  = (const float*)d_in[12];
  const float* bv  = (const float*)d_in[13];
  const float* Wp  = (const float*)d_in[14];
  const float* bp  = (const float*)d_in[15];
  const float* g2  = (const float*)d_in[16];
  const float* b2  = (const float*)d_in[17];
  const float* Wf1 = (const float*)d_in[18];
  const float* bf1 = (const float*)d_in[19];
  const float* Wf2 = (const float*)d_in[20];
  const float* bf2 = (const float*)d_in[21];

  char* ws = (char*)d_ws;
  short* wt_oa   = (short*)(ws + 0);          // 384x256 frag-major (196608 B)
  short* wt_v    = (short*)(ws + 196608);     // frag-major (131072 B)
  short* wt_p    = (short*)(ws + 327680);     // frag-major packed
  short* wt_f1   = (short*)(ws + 458752);     // frag-major packed
  short* wt_f2   = (short*)(ws + 983040);     // frag-major packed
  short* qnb     = (short*)(ws + 1507328);    // 16384x256 bf16 (LN1, no pos)
  short* oabuf   = (short*)(ws + 26673152);   // 16384x288 bf16 (9.4 MB)
  short* vproj   = (short*)(ws + 45547520);   // 12600x256 bf16
  short* sampled = (short*)(ws + 51998720);   // 16384x256 bf16
  float* outp = (float*)d_out;

  // 1. weight convert + frag-major pack (tiny)
  prep_w<<<1792, 256, 0, stream>>>(Wo, Wa, Wv, Wp, Wf1, Wf2,
                                   wt_oa, wt_v, wt_p, wt_f1, wt_f2);
  // 2. LN1+oa GEMM (256 blocks) + vconvert+v GEMM (197 blocks)
  gemm_oa_v2<<<453, 1024, 0, stream>>>(query, query_pos, g1, b1,
                                       wt_oa, bo, ba, qnb, oabuf,
                                       value, wt_v, bv, vproj);
  // 3. fused prep+gather -> sampled bf16
  deform_fused<<<2048, 256, 0, stream>>>(vproj, oabuf, ref_pts, sampled);
  // 4. merged Wp-GEMM + LN2 + MLP (64-row block, 128 KB LDS, no spill)
  wp_mlp<<<256, 1024, 0, stream>>>(sampled, wt_p, bp, qnb, query, g2, b2,
                                   wt_f1, bf1, wt_f2, bf2, outp);
}